// Round 1
// baseline (52.435 us; speedup 1.0000x reference)
//
#include <hip/hip_runtime.h>
#include <float.h>
#include <math.h>

#define BB 8
#define PP 4096
#define PTS_PER_BLOCK 256
#define THREADS 1024
#define NCHUNKS (PP / PTS_PER_BLOCK)      // 16
#define JSPLIT  (THREADS / PTS_PER_BLOCK) // 4 threads per query point
#define JCHUNK  (PP / JSPLIT)             // 1024 neighbors per thread

__global__ __launch_bounds__(THREADS) void chamfer_min_kernel(
    const float* __restrict__ y1, const float* __restrict__ y2,
    float* __restrict__ partial)
{
    __shared__ float s[PP * 3];        // 48 KB: whole target cloud
    __shared__ float smin[THREADS];    // per-thread partial mins
    __shared__ float ssum[4];          // per-wave sums (4 waves participate)

    const int bid    = blockIdx.x;
    const int dir    = bid / (BB * NCHUNKS);
    const int rem    = bid % (BB * NCHUNKS);
    const int cloud  = rem / NCHUNKS;
    const int chunk  = rem % NCHUNKS;

    const float* src = (dir == 0) ? y1 : y2;
    const float* tgt = (dir == 0) ? y2 : y1;
    const float* __restrict__ tgt_base = tgt + (size_t)cloud * PP * 3;
    const float* __restrict__ src_base = src + (size_t)cloud * PP * 3;

    const int tid = threadIdx.x;

    // Cooperative, coalesced stage of the target cloud into LDS.
    #pragma unroll
    for (int idx = tid; idx < PP * 3; idx += THREADS)
        s[idx] = tgt_base[idx];
    __syncthreads();

    const int pt  = tid & (PTS_PER_BLOCK - 1);  // which query point in the chunk
    const int seg = tid >> 8;                   // which neighbor quarter
    const int p   = chunk * PTS_PER_BLOCK + pt;

    const float ax = src_base[p * 3 + 0];
    const float ay = src_base[p * 3 + 1];
    const float az = src_base[p * 3 + 2];

    float m0 = FLT_MAX, m1 = FLT_MAX, m2 = FLT_MAX, m3 = FLT_MAX;
    const int j0 = seg * JCHUNK;

    for (int j = j0; j < j0 + JCHUNK; j += 4) {
        const int base = j * 3;
        float dx0 = ax - s[base + 0];
        float dy0 = ay - s[base + 1];
        float dz0 = az - s[base + 2];
        float d0  = dx0 * dx0 + dy0 * dy0 + dz0 * dz0;

        float dx1 = ax - s[base + 3];
        float dy1 = ay - s[base + 4];
        float dz1 = az - s[base + 5];
        float d1  = dx1 * dx1 + dy1 * dy1 + dz1 * dz1;

        float dx2 = ax - s[base + 6];
        float dy2 = ay - s[base + 7];
        float dz2 = az - s[base + 8];
        float d2  = dx2 * dx2 + dy2 * dy2 + dz2 * dz2;

        float dx3 = ax - s[base + 9];
        float dy3 = ay - s[base + 10];
        float dz3 = az - s[base + 11];
        float d3  = dx3 * dx3 + dy3 * dy3 + dz3 * dz3;

        m0 = fminf(m0, d0);
        m1 = fminf(m1, d1);
        m2 = fminf(m2, d2);
        m3 = fminf(m3, d3);
    }

    smin[tid] = fminf(fminf(m0, m1), fminf(m2, m3));
    __syncthreads();

    // Threads 0..255 (seg==0) combine the 4 quarter-mins for their point.
    float dist = 0.0f;
    if (seg == 0) {
        float mm = fminf(fminf(smin[pt], smin[pt + 256]),
                         fminf(smin[pt + 512], smin[pt + 768]));
        dist = sqrtf(mm);
        // wave64 shuffle reduction (threads 0..255 = waves 0..3)
        #pragma unroll
        for (int off = 32; off > 0; off >>= 1)
            dist += __shfl_down(dist, off);
        if ((tid & 63) == 0)
            ssum[tid >> 6] = dist;
    }
    __syncthreads();
    if (tid == 0)
        partial[bid] = ssum[0] + ssum[1] + ssum[2] + ssum[3];
}

__global__ __launch_bounds__(256) void chamfer_reduce_kernel(
    const float* __restrict__ partial, float* __restrict__ out, int nblocks)
{
    __shared__ float ssum[4];
    const int tid = threadIdx.x;
    float v = (tid < nblocks) ? partial[tid] : 0.0f;
    #pragma unroll
    for (int off = 32; off > 0; off >>= 1)
        v += __shfl_down(v, off);
    if ((tid & 63) == 0)
        ssum[tid >> 6] = v;
    __syncthreads();
    if (tid == 0)
        out[0] = (ssum[0] + ssum[1] + ssum[2] + ssum[3]) * (1.0f / (float)(BB * PP));
}

extern "C" void kernel_launch(void* const* d_in, const int* in_sizes, int n_in,
                              void* d_out, int out_size, void* d_ws, size_t ws_size,
                              hipStream_t stream) {
    const float* y1 = (const float*)d_in[0];
    const float* y2 = (const float*)d_in[1];
    float* partial  = (float*)d_ws;   // 256 floats of scratch
    float* out      = (float*)d_out;

    const int nblocks = 2 * BB * NCHUNKS;  // 256: (dir, cloud, chunk)
    chamfer_min_kernel<<<nblocks, THREADS, 0, stream>>>(y1, y2, partial);
    chamfer_reduce_kernel<<<1, 256, 0, stream>>>(partial, out, nblocks);
}

// Round 2
// 30.460 us; speedup vs baseline: 1.7214x; 1.7214x over previous
//
#include <hip/hip_runtime.h>
#include <float.h>
#include <math.h>

#define BB 8
#define PP 4096
#define QW 512      // queries per block (all 16 waves share them)
#define QPL 8       // queries per lane (8 * 64 lanes = 512)
#define SEGN 128    // neighbors per wave
#define HALF 2048   // neighbors per block (seghalf)

// Pass 1: per (dir, cloud, qgroup, seghalf) block, compute per-query
// min over 2048 neighbors of t = |c|^2/2 - a.c  (argmin-equivalent to d^2).
__global__ __launch_bounds__(1024) void chamfer_pass1(
    const float* __restrict__ y1, const float* __restrict__ y2,
    float* __restrict__ ws)
{
    __shared__ float4 nb[HALF];       // 32 KB: (x, y, z, |c|^2/2)
    __shared__ float pmin[16][QW];    // 32 KB: per-wave partial mins

    const int bid   = blockIdx.x;
    const int sh    = bid & 1;
    const int qg    = (bid >> 1) & 7;
    const int cloud = (bid >> 4) & 7;
    const int dir   = bid >> 7;

    const float* src = (dir == 0) ? y1 : y2;
    const float* tgt = (dir == 0) ? y2 : y1;
    const float* __restrict__ tgt_base = tgt + ((size_t)cloud * PP + (size_t)sh * HALF) * 3;
    const float* __restrict__ src_base = src + (size_t)cloud * PP * 3;

    const int tid  = threadIdx.x;
    const int lane = tid & 63;
    const int w    = tid >> 6;

    // Stage 2048 neighbors into LDS as (x,y,z,h), 2 per thread, coalesced read.
    {
        const int n0 = tid * 2;
        const float* g = tgt_base + (size_t)n0 * 3;
        float x0 = g[0], ya = g[1], z0 = g[2];
        float x1 = g[3], yb = g[4], z1 = g[5];
        nb[n0]     = make_float4(x0, ya, z0, 0.5f * (x0 * x0 + ya * ya + z0 * z0));
        nb[n0 + 1] = make_float4(x1, yb, z1, 0.5f * (x1 * x1 + yb * yb + z1 * z1));
    }

    // Each lane owns 8 query points (pre-negated for the FMA chain).
    float nax[QPL], nay[QPL], naz[QPL], acc[QPL];
    #pragma unroll
    for (int k = 0; k < QPL; ++k) {
        const int p = qg * QW + lane + k * 64;
        const float* q = src_base + (size_t)p * 3;
        nax[k] = -q[0]; nay[k] = -q[1]; naz[k] = -q[2];
        acc[k] = FLT_MAX;
    }
    __syncthreads();

    // Main loop: wave-uniform broadcast ds_read_b128, amortized over 8 queries.
    const int jbase = w * SEGN;
    for (int i = 0; i < SEGN; i += 4) {
        float4 c0 = nb[jbase + i + 0];
        float4 c1 = nb[jbase + i + 1];
        float4 c2 = nb[jbase + i + 2];
        float4 c3 = nb[jbase + i + 3];
        #pragma unroll
        for (int k = 0; k < QPL; ++k) {
            float t0 = fmaf(nax[k], c0.x, fmaf(nay[k], c0.y, fmaf(naz[k], c0.z, c0.w)));
            float t1 = fmaf(nax[k], c1.x, fmaf(nay[k], c1.y, fmaf(naz[k], c1.z, c1.w)));
            acc[k] = fminf(fminf(t0, t1), acc[k]);   // v_min3 pattern
            float t2 = fmaf(nax[k], c2.x, fmaf(nay[k], c2.y, fmaf(naz[k], c2.z, c2.w)));
            float t3 = fmaf(nax[k], c3.x, fmaf(nay[k], c3.y, fmaf(naz[k], c3.z, c3.w)));
            acc[k] = fminf(fminf(t2, t3), acc[k]);
        }
    }

    #pragma unroll
    for (int k = 0; k < QPL; ++k)
        pmin[w][lane + k * 64] = acc[k];
    __syncthreads();

    // Combine the 16 waves' partial mins; write per-(block, query) result.
    if (tid < QW) {
        float m = pmin[0][tid];
        #pragma unroll
        for (int ww = 1; ww < 16; ++ww)
            m = fminf(m, pmin[ww][tid]);
        ws[(size_t)bid * QW + tid] = m;   // flat = combo*1024 + sh*512 + q
    }
}

// Pass 2: per query, combine the 2 seghalves, d = sqrt(aa + 2*min_t), block-sum.
__global__ __launch_bounds__(1024) void chamfer_pass2(
    const float* __restrict__ y1, const float* __restrict__ y2,
    const float* __restrict__ ws, float* __restrict__ partial)
{
    __shared__ float ssum[16];
    const int gq    = blockIdx.x * 1024 + threadIdx.x;   // 0..65535
    const int dir   = gq >> 15;
    const int pidx  = gq & 32767;                        // cloud*4096 + p
    const int combo = gq >> 9;                           // (dir,cloud,qg)
    const int q     = gq & 511;

    const float* src = (dir == 0) ? y1 : y2;
    const float  m   = fminf(ws[(size_t)combo * 1024 + q],
                             ws[(size_t)combo * 1024 + 512 + q]);
    const float* a   = src + (size_t)pidx * 3;
    const float  aa  = a[0] * a[0] + a[1] * a[1] + a[2] * a[2];
    float d = sqrtf(fmaxf(0.0f, fmaf(2.0f, m, aa)));

    #pragma unroll
    for (int off = 32; off > 0; off >>= 1)
        d += __shfl_down(d, off);
    if ((threadIdx.x & 63) == 0)
        ssum[threadIdx.x >> 6] = d;
    __syncthreads();
    if (threadIdx.x < 16) {
        float v = ssum[threadIdx.x];
        #pragma unroll
        for (int off = 8; off > 0; off >>= 1)
            v += __shfl_down(v, off);
        if (threadIdx.x == 0)
            partial[blockIdx.x] = v;
    }
}

// Pass 3: sum 64 block partials, normalize by B*P (gives d1 + d2).
__global__ __launch_bounds__(64) void chamfer_pass3(
    const float* __restrict__ partial, float* __restrict__ out)
{
    float v = partial[threadIdx.x];
    #pragma unroll
    for (int off = 32; off > 0; off >>= 1)
        v += __shfl_down(v, off);
    if (threadIdx.x == 0)
        out[0] = v * (1.0f / (float)(BB * PP));
}

extern "C" void kernel_launch(void* const* d_in, const int* in_sizes, int n_in,
                              void* d_out, int out_size, void* d_ws, size_t ws_size,
                              hipStream_t stream) {
    const float* y1 = (const float*)d_in[0];
    const float* y2 = (const float*)d_in[1];
    float* ws      = (float*)d_ws;            // 131072 floats (512 KB)
    float* partial = ws + 131072;             // +64 floats
    float* out     = (float*)d_out;

    chamfer_pass1<<<256, 1024, 0, stream>>>(y1, y2, ws);
    chamfer_pass2<<<64, 1024, 0, stream>>>(y1, y2, ws, partial);
    chamfer_pass3<<<1, 64, 0, stream>>>(partial, out);
}